// Round 2
// baseline (587.925 us; speedup 1.0000x reference)
//
#include <hip/hip_runtime.h>

typedef _Float16 h16;
typedef __attribute__((ext_vector_type(8))) _Float16 half8;
typedef __attribute__((ext_vector_type(4))) float floatx4;

__device__ __forceinline__ h16 f2h(float f){ return (h16)f; }
__device__ __forceinline__ float h2f(h16 s){ return (float)s; }

// ---------------- f32 -> f16 convert (8 elements/thread) ----------------
__global__ __launch_bounds__(256) void hs_to_f16(const float* __restrict__ in,
                                                 h16* __restrict__ out, int n8){
  int i = blockIdx.x * 256 + threadIdx.x;
  if (i >= n8) return;
  floatx4 a = ((const floatx4*)in)[2*i];
  floatx4 b = ((const floatx4*)in)[2*i+1];
  half8 o;
  o[0]=f2h(a[0]); o[1]=f2h(a[1]); o[2]=f2h(a[2]); o[3]=f2h(a[3]);
  o[4]=f2h(b[0]); o[5]=f2h(b[1]); o[6]=f2h(b[2]); o[7]=f2h(b[3]);
  ((half8*)out)[i] = o;
}

// ------- weight transpose: dst[n][k] = src[k][n], f32 -> f16 ------------
__global__ __launch_bounds__(256) void wtrans(const float* __restrict__ wq,
                                              const float* __restrict__ wk,
                                              const float* __restrict__ wv,
                                              const float* __restrict__ wo,
                                              h16* __restrict__ wqkv_t,
                                              h16* __restrict__ wo_t){
  __shared__ float tile[32][33];
  int z = blockIdx.z;
  const float* src = (z==0)? wq : (z==1)? wk : (z==2)? wv : wo;
  h16* dst = (z<3) ? (wqkv_t + (size_t)z*2048*2048) : wo_t;
  int r0 = blockIdx.y*32, c0 = blockIdx.x*32;
  int t = threadIdx.x;
  int tr = t>>5, tc = t&31;               // 8 rows x 32 cols per pass
  for (int p=0;p<4;++p)
    tile[p*8+tr][tc] = src[(size_t)(r0+p*8+tr)*2048 + c0 + tc];
  __syncthreads();
  for (int p=0;p<4;++p)
    dst[(size_t)(c0+p*8+tr)*2048 + r0 + tc] = f2h(tile[tc][p*8+tr]);
}

// ---------------- f16 GEMM: C[M][N] = A[M][K] * Bt[N][K]^T --------------
// 128x128 tile, BK=32, 256 thr = 4 waves in 2x2 grid, each wave 64x64.
template<bool OUT_F32>
__global__ __launch_bounds__(256) void gemm_bt(const h16* __restrict__ A,
                                               const h16* __restrict__ Bt,
                                               void* __restrict__ Cout,
                                               int M, int N, int K){
  __shared__ h16 a_lds[128*40];  // pad 32 -> 40 (2-way bank aliasing only)
  __shared__ h16 b_lds[128*40];
  const int t = threadIdx.x;
  const int m0 = blockIdx.y * 128, n0 = blockIdx.x * 128;
  const int wave = t >> 6, lane = t & 63, quad = lane >> 4, l16 = lane & 15;
  const int wm = (wave & 1) * 64, wn = (wave >> 1) * 64;
  floatx4 zero4 = {0.f,0.f,0.f,0.f};
  floatx4 acc[4][4];
  for (int mi=0;mi<4;++mi) for (int ni=0;ni<4;++ni) acc[mi][ni] = zero4;

  for (int k0 = 0; k0 < K; k0 += 32){
    for (int h = 0; h < 2; ++h){
      int c = h*256 + t;
      int row = c >> 2, kc = c & 3;
      half8 va = *(const half8*)(A  + (size_t)(m0+row)*K + k0 + kc*8);
      *(half8*)(a_lds + row*40 + kc*8) = va;
      half8 vb = *(const half8*)(Bt + (size_t)(n0+row)*K + k0 + kc*8);
      *(half8*)(b_lds + row*40 + kc*8) = vb;
    }
    __syncthreads();
    half8 af[4], bfr[4];
    for (int mi=0;mi<4;++mi) af[mi]  = *(const half8*)(a_lds + (wm + mi*16 + l16)*40 + quad*8);
    for (int ni=0;ni<4;++ni) bfr[ni] = *(const half8*)(b_lds + (wn + ni*16 + l16)*40 + quad*8);
    for (int mi=0;mi<4;++mi)
      for (int ni=0;ni<4;++ni)
        acc[mi][ni] = __builtin_amdgcn_mfma_f32_16x16x32_f16(af[mi], bfr[ni], acc[mi][ni], 0,0,0);
    __syncthreads();
  }
  // epilogue: C/D layout col=lane&15 (N), row=quad*4+r (M)  [m89/m91 verified]
  for (int mi=0;mi<4;++mi)
    for (int ni=0;ni<4;++ni)
      for (int r=0;r<4;++r){
        int row = m0 + wm + mi*16 + quad*4 + r;
        int col = n0 + wn + ni*16 + l16;
        float v = acc[mi][ni][r];
        if (OUT_F32) ((float*)Cout)[(size_t)row*N + col] = v;
        else         ((h16*)Cout)[(size_t)row*N + col] = f2h(v);
      }
}

// -------- rotary + layout: qkv f16 [4096][6144] -> qT,kT [B,H,S,128],
//          vT [B,H,128,S]  (all f16) ----------------------------------
__global__ __launch_bounds__(256) void rotary_split(const h16* __restrict__ qkv,
                                                    h16* __restrict__ qT,
                                                    h16* __restrict__ kT,
                                                    h16* __restrict__ vT){
  const int st = blockIdx.x, bh = blockIdx.y;
  const int b = bh >> 4, h = bh & 15;
  const int s0 = st * 64;
  const int t = threadIdx.x;
  // q and k rotary: 64 s-rows x 64 d-pairs, sincos shared between q and k
  for (int i = t; i < 4096; i += 256){
    int srow = i >> 6;
    int d = i & 63;
    int sg = s0 + srow;
    size_t m = (size_t)b*2048 + sg;
    size_t baseq = m*6144 + h*128;
    float inv = __expf(-0.14391157f * (float)d);   // ln(10000)/64
    float ang = (float)sg * inv;
    float sn, cs;
    sincosf(ang, &sn, &cs);
    size_t dst = ((size_t)bh*2048 + sg)*128 + d;
    {
      float x1 = h2f(qkv[baseq + d]);
      float x2 = h2f(qkv[baseq + d + 64]);
      qT[dst]      = f2h(x1*cs - x2*sn);
      qT[dst + 64] = f2h(x2*cs + x1*sn);
    }
    {
      float x1 = h2f(qkv[baseq + 2048 + d]);
      float x2 = h2f(qkv[baseq + 2048 + d + 64]);
      kT[dst]      = f2h(x1*cs - x2*sn);
      kT[dst + 64] = f2h(x2*cs + x1*sn);
    }
  }
  // v transpose: vT[bh][d][s] = v[b,s][h*128+d]; lanes iterate s fastest
  for (int i = t; i < 8192; i += 256){
    int d = i >> 6, soff = i & 63;
    size_t m = (size_t)b*2048 + s0 + soff;
    h16 val = qkv[m*6144 + 4096 + h*128 + d];
    vT[((size_t)bh*128 + d)*2048 + s0 + soff] = val;
  }
}

// ---------------- flash attention (lingvo softmax + tanh cap) ------------
// grid (qt=S/64, h, b); 256 thr = 4 waves, each wave 16 q-rows.
__global__ __launch_bounds__(256) void flash_attn(const h16* __restrict__ qT,
                                                  const h16* __restrict__ kT,
                                                  const h16* __restrict__ vT,
                                                  h16* __restrict__ O){
  __shared__ h16 k_lds[64*136];    // [kn][kd], pad 128 -> 136
  __shared__ h16 v_lds[128*72];    // [d][s],  pad 64 -> 72
  __shared__ h16 p_lds[4*16*72];   // per-wave 16 x 64 (pad 72)
  const int t = threadIdx.x, wave = t>>6, lane = t&63, quad = lane>>4, l16 = lane&15;
  const int qt = blockIdx.x, h = blockIdx.y, b = blockIdx.z;
  const int bh = b*16 + h;
  const int q0 = qt*64;
  const size_t qrow = (size_t)bh*2048 + q0 + wave*16 + l16;
  half8 aq[4];
  for (int kc=0;kc<4;++kc) aq[kc] = *(const half8*)(qT + qrow*128 + kc*32 + quad*8);
  floatx4 zero4 = {0.f,0.f,0.f,0.f};
  floatx4 acc_o[8];
  for (int nt=0;nt<8;++nt) acc_o[nt] = zero4;
  float mrow[4] = {0.f,0.f,0.f,0.f};  // lingvo: max clamped at 0
  float lrow[4] = {1.f,1.f,1.f,1.f};  // phantom exp(0-0)=1 in denom

  for (int kt = 0; kt <= qt; ++kt){
    const int kbase = kt*64;
    {
      const h16* src = kT + ((size_t)bh*2048 + kbase)*128;
      for (int p=0;p<4;++p){
        int row = p*16 + (t>>4), ch = t&15;
        *(half8*)(k_lds + row*136 + ch*8) = *(const half8*)(src + (size_t)row*128 + ch*8);
      }
      const h16* vsrc = vT + (size_t)bh*128*2048 + kbase;
      for (int p=0;p<4;++p){
        int d = p*32 + (t>>3), ch = t&7;
        *(half8*)(v_lds + d*72 + ch*8) = *(const half8*)(vsrc + (size_t)d*2048 + ch*8);
      }
    }
    __syncthreads();
    // S = Q K^T  (16 rows x 64 cols per wave)
    floatx4 s[4];
    for (int ni=0;ni<4;++ni){
      floatx4 a = zero4;
      for (int kc=0;kc<4;++kc){
        half8 bk = *(const half8*)(k_lds + (ni*16 + l16)*136 + kc*32 + quad*8);
        a = __builtin_amdgcn_mfma_f32_16x16x32_f16(aq[kc], bk, a, 0,0,0);
      }
      s[ni] = a;
    }
    // cap, mask, online lingvo softmax
    float pm[4][4];
    float tmax[4] = {-1e30f,-1e30f,-1e30f,-1e30f};
    for (int ni=0;ni<4;++ni){
      int col = kbase + ni*16 + l16;
      for (int r=0;r<4;++r){
        int row = q0 + wave*16 + quad*4 + r;
        float x = 50.f * tanhf(s[ni][r] * 0.02f);
        if (col > row) x = -1e30f;
        pm[ni][r] = x;
        tmax[r] = fmaxf(tmax[r], x);
      }
    }
    for (int r=0;r<4;++r)
      for (int off=1; off<16; off<<=1)
        tmax[r] = fmaxf(tmax[r], __shfl_xor(tmax[r], off, 16));
    float alpha[4], mnew[4], rsum[4];
    for (int r=0;r<4;++r){
      mnew[r] = fmaxf(mrow[r], tmax[r]);
      alpha[r] = __expf(mrow[r] - mnew[r]);
      mrow[r] = mnew[r];
      rsum[r] = 0.f;
    }
    for (int ni=0;ni<4;++ni)
      for (int r=0;r<4;++r){
        float p = __expf(pm[ni][r] - mnew[r]);
        pm[ni][r] = p;
        rsum[r] += p;
      }
    for (int r=0;r<4;++r){
      for (int off=1; off<16; off<<=1) rsum[r] += __shfl_xor(rsum[r], off, 16);
      lrow[r] = alpha[r]*lrow[r] + rsum[r];
    }
    for (int nt=0;nt<8;++nt)
      for (int r=0;r<4;++r) acc_o[nt][r] *= alpha[r];
    // P: C-layout -> A-layout via wave-private LDS (m120 pattern)
    h16* pw = p_lds + wave*16*72;
    for (int ni=0;ni<4;++ni)
      for (int r=0;r<4;++r)
        pw[(quad*4+r)*72 + ni*16 + l16] = f2h(pm[ni][r]);
    __builtin_amdgcn_wave_barrier();
    half8 ap0 = *(const half8*)(pw + l16*72 + quad*8);
    half8 ap1 = *(const half8*)(pw + l16*72 + 32 + quad*8);
    for (int nt=0;nt<8;++nt){
      half8 bv0 = *(const half8*)(v_lds + (nt*16 + l16)*72 + quad*8);
      half8 bv1 = *(const half8*)(v_lds + (nt*16 + l16)*72 + 32 + quad*8);
      acc_o[nt] = __builtin_amdgcn_mfma_f32_16x16x32_f16(ap0, bv0, acc_o[nt], 0,0,0);
      acc_o[nt] = __builtin_amdgcn_mfma_f32_16x16x32_f16(ap1, bv1, acc_o[nt], 0,0,0);
    }
    __syncthreads();
  }
  float invl[4];
  for (int r=0;r<4;++r) invl[r] = 1.0f / lrow[r];
  for (int nt=0;nt<8;++nt)
    for (int r=0;r<4;++r){
      int row = q0 + wave*16 + quad*4 + r;
      int col = h*128 + nt*16 + l16;
      O[((size_t)b*2048 + row)*2048 + col] = f2h(acc_o[nt][r] * invl[r]);
    }
}

extern "C" void kernel_launch(void* const* d_in, const int* in_sizes, int n_in,
                              void* d_out, int out_size, void* d_ws, size_t ws_size,
                              hipStream_t stream){
  (void)in_sizes; (void)n_in; (void)out_size; (void)ws_size;
  const float* hs = (const float*)d_in[0];
  const float* wq = (const float*)d_in[1];
  const float* wk = (const float*)d_in[2];
  const float* wv = (const float*)d_in[3];
  const float* wo = (const float*)d_in[4];

  char* ws = (char*)d_ws;
  size_t off = 0;
  h16* hs_f   = (h16*)(ws + off); off += (size_t)4096*2048*2;   // 16.8 MB
  h16* wqkv_t = (h16*)(ws + off); off += (size_t)6144*2048*2;   // 25.2 MB
  h16* wo_t   = (h16*)(ws + off); off += (size_t)2048*2048*2;   //  8.4 MB
  h16* qkv    = (h16*)(ws + off); off += (size_t)4096*6144*2;   // 50.3 MB
  h16* qT     = (h16*)(ws + off); off += (size_t)4096*2048*2;   // 16.8 MB
  h16* kT     = (h16*)(ws + off); off += (size_t)4096*2048*2;   // 16.8 MB
  h16* vT     = (h16*)(ws + off); off += (size_t)4096*2048*2;   // 16.8 MB
  h16* obuf   = qkv;  // qkv dead after rotary_split; reuse as O buffer

  hs_to_f16<<<dim3(4096), 256, 0, stream>>>(hs, hs_f, 4096*2048/8);
  wtrans<<<dim3(64,64,4), 256, 0, stream>>>(wq, wk, wv, wo, wqkv_t, wo_t);
  gemm_bt<false><<<dim3(48,32), 256, 0, stream>>>(hs_f, wqkv_t, (void*)qkv, 4096, 6144, 2048);
  rotary_split<<<dim3(32,32), 256, 0, stream>>>(qkv, qT, kT, vT);
  flash_attn<<<dim3(32,16,2), 256, 0, stream>>>(qT, kT, vT, obuf);
  gemm_bt<true><<<dim3(16,32), 256, 0, stream>>>(obuf, wo_t, d_out, 4096, 2048, 2048);
}

// Round 3
// 477.680 us; speedup vs baseline: 1.2308x; 1.2308x over previous
//
#include <hip/hip_runtime.h>

typedef _Float16 h16;
typedef __attribute__((ext_vector_type(8))) _Float16 half8;
typedef __attribute__((ext_vector_type(4))) float floatx4;

__device__ __forceinline__ h16 f2h(float f){ return (h16)f; }
__device__ __forceinline__ float h2f(h16 s){ return (float)s; }

#define GL2LDS(gp, lp) __builtin_amdgcn_global_load_lds( \
    (const __attribute__((address_space(1))) void*)(gp), \
    (__attribute__((address_space(3))) void*)(lp), 16, 0, 0)

// ---------------- f32 -> f16 convert (8 elements/thread) ----------------
__global__ __launch_bounds__(256) void hs_to_f16(const float* __restrict__ in,
                                                 h16* __restrict__ out, int n8){
  int i = blockIdx.x * 256 + threadIdx.x;
  if (i >= n8) return;
  floatx4 a = ((const floatx4*)in)[2*i];
  floatx4 b = ((const floatx4*)in)[2*i+1];
  half8 o;
  o[0]=f2h(a[0]); o[1]=f2h(a[1]); o[2]=f2h(a[2]); o[3]=f2h(a[3]);
  o[4]=f2h(b[0]); o[5]=f2h(b[1]); o[6]=f2h(b[2]); o[7]=f2h(b[3]);
  ((half8*)out)[i] = o;
}

// ------- weight transpose: dst[n][k] = src[k][n], f32 -> f16 ------------
__global__ __launch_bounds__(256) void wtrans(const float* __restrict__ wq,
                                              const float* __restrict__ wk,
                                              const float* __restrict__ wv,
                                              const float* __restrict__ wo,
                                              h16* __restrict__ wqkv_t,
                                              h16* __restrict__ wo_t){
  __shared__ float tile[32][33];
  int z = blockIdx.z;
  const float* src = (z==0)? wq : (z==1)? wk : (z==2)? wv : wo;
  h16* dst = (z<3) ? (wqkv_t + (size_t)z*2048*2048) : wo_t;
  int r0 = blockIdx.y*32, c0 = blockIdx.x*32;
  int t = threadIdx.x;
  int tr = t>>5, tc = t&31;               // 8 rows x 32 cols per pass
  for (int p=0;p<4;++p)
    tile[p*8+tr][tc] = src[(size_t)(r0+p*8+tr)*2048 + c0 + tc];
  __syncthreads();
  for (int p=0;p<4;++p)
    dst[(size_t)(c0+p*8+tr)*2048 + r0 + tc] = f2h(tile[tc][p*8+tr]);
}

// ---------------- f16 GEMM (m97 pattern): C = A * Bt^T ------------------
// 128x128 tile, BK=32, 256 thr = 4 waves 2x2, global_load_lds width=16.
template<bool OUT_F32>
__global__ __launch_bounds__(256) void gemm_bt(const h16* __restrict__ A,
                                               const h16* __restrict__ Bt,
                                               void* __restrict__ Cout,
                                               int M, int N, int K){
  __shared__ h16 a_lds[128*32];   // unpadded: required by global_load_lds layout
  __shared__ h16 b_lds[128*32];
  const int t = threadIdx.x;
  const int m0 = blockIdx.y * 128, n0 = blockIdx.x * 128;
  const int wave = t >> 6, lane = t & 63, quad = lane >> 4, l16 = lane & 15;
  const int wm = (wave & 1) * 64, wn = (wave >> 1) * 64;
  // staging: pass p covers rows p*64 + wave*16 + (lane>>2), 16B chunk lane&3
  const int srow = wave*16 + (lane >> 2);
  const int schunk = lane & 3;
  const h16* Abase = A  + (size_t)(m0 + srow)*K + schunk*8;
  const h16* Bbase = Bt + (size_t)(n0 + srow)*K + schunk*8;
  h16* aL = a_lds + wave*512;   // + lane*8 added by HW (lane x 16B)
  h16* bL = b_lds + wave*512;

  floatx4 zero4 = {0.f,0.f,0.f,0.f};
  floatx4 acc[4][4];
  for (int mi=0;mi<4;++mi) for (int ni=0;ni<4;++ni) acc[mi][ni] = zero4;

  for (int k0 = 0; k0 < K; k0 += 32){
    GL2LDS(Abase + k0,              aL);
    GL2LDS(Abase + (size_t)64*K+k0, aL + 2048);
    GL2LDS(Bbase + k0,              bL);
    GL2LDS(Bbase + (size_t)64*K+k0, bL + 2048);
    __syncthreads();
    half8 af[4], bfr[4];
    for (int mi=0;mi<4;++mi) af[mi]  = *(const half8*)(a_lds + (wm + mi*16 + l16)*32 + quad*8);
    for (int ni=0;ni<4;++ni) bfr[ni] = *(const half8*)(b_lds + (wn + ni*16 + l16)*32 + quad*8);
    for (int mi=0;mi<4;++mi)
      for (int ni=0;ni<4;++ni)
        acc[mi][ni] = __builtin_amdgcn_mfma_f32_16x16x32_f16(af[mi], bfr[ni], acc[mi][ni], 0,0,0);
    __syncthreads();
  }
  for (int mi=0;mi<4;++mi)
    for (int ni=0;ni<4;++ni)
      for (int r=0;r<4;++r){
        int row = m0 + wm + mi*16 + quad*4 + r;
        int col = n0 + wn + ni*16 + l16;
        float v = acc[mi][ni][r];
        if (OUT_F32) ((float*)Cout)[(size_t)row*N + col] = v;
        else         ((h16*)Cout)[(size_t)row*N + col] = f2h(v);
      }
}

// -------- rotary + layout: qkv f16 [4096][6144] -> qT,kT [B,H,S,128],
//          vT [B,H,128,S]  (all f16) ----------------------------------
__global__ __launch_bounds__(256) void rotary_split(const h16* __restrict__ qkv,
                                                    h16* __restrict__ qT,
                                                    h16* __restrict__ kT,
                                                    h16* __restrict__ vT){
  const int st = blockIdx.x, bh = blockIdx.y;
  const int b = bh >> 4, h = bh & 15;
  const int s0 = st * 64;
  const int t = threadIdx.x;
  for (int i = t; i < 4096; i += 256){
    int srow = i >> 6;
    int d = i & 63;
    int sg = s0 + srow;
    size_t m = (size_t)b*2048 + sg;
    size_t baseq = m*6144 + h*128;
    float inv = __expf(-0.14391157f * (float)d);   // ln(10000)/64
    float ang = (float)sg * inv;
    float sn, cs;
    __sincosf(ang, &sn, &cs);
    size_t dst = ((size_t)bh*2048 + sg)*128 + d;
    {
      float x1 = h2f(qkv[baseq + d]);
      float x2 = h2f(qkv[baseq + d + 64]);
      qT[dst]      = f2h(x1*cs - x2*sn);
      qT[dst + 64] = f2h(x2*cs + x1*sn);
    }
    {
      float x1 = h2f(qkv[baseq + 2048 + d]);
      float x2 = h2f(qkv[baseq + 2048 + d + 64]);
      kT[dst]      = f2h(x1*cs - x2*sn);
      kT[dst + 64] = f2h(x2*cs + x1*sn);
    }
  }
  for (int i = t; i < 8192; i += 256){
    int d = i >> 6, soff = i & 63;
    size_t m = (size_t)b*2048 + s0 + soff;
    h16 val = qkv[m*6144 + 4096 + h*128 + d];
    vT[((size_t)bh*128 + d)*2048 + s0 + soff] = val;
  }
}

// ---------------- flash attention (lingvo softmax + tanh cap) ------------
// grid (16, h, b); block pairs q-tiles {x, 31-x} -> 33 kt per block (balanced).
// Prefetch next K/V tile into regs; fast tanh; mask only on diagonal tile.
__global__ __launch_bounds__(256) void flash_attn(const h16* __restrict__ qT,
                                                  const h16* __restrict__ kT,
                                                  const h16* __restrict__ vT,
                                                  h16* __restrict__ O){
  __shared__ h16 k_lds[64*136];    // [kn][kd], pad 128 -> 136
  __shared__ h16 v_lds[128*72];    // [d][s],  pad 64 -> 72
  __shared__ h16 p_lds[4*16*72];   // per-wave 16 x 64 (pad 72)
  const int t = threadIdx.x, wave = t>>6, lane = t&63, quad = lane>>4, l16 = lane&15;
  const int h = blockIdx.y, b = blockIdx.z;
  const int bh = b*16 + h;
  // staging index precompute
  const int krow = t>>4, kch = t&15;         // K: rows krow, krow+16, +32, +48
  const int vrow = t>>3, vch = t&7;          // V: d = vrow, +32, +64, +96
  const h16* kTb = kT + (size_t)bh*2048*128;
  const h16* vTb = vT + (size_t)bh*128*2048;
  floatx4 zero4 = {0.f,0.f,0.f,0.f};

  for (int half = 0; half < 2; ++half){
    const int qt = half ? 31 - (int)blockIdx.x : (int)blockIdx.x;
    const int q0 = qt*64;
    const size_t qrow = (size_t)bh*2048 + q0 + wave*16 + l16;
    half8 aq[4];
    for (int kc=0;kc<4;++kc) aq[kc] = *(const half8*)(qT + qrow*128 + kc*32 + quad*8);
    floatx4 acc_o[8];
    for (int nt=0;nt<8;++nt) acc_o[nt] = zero4;
    float mrow[4] = {0.f,0.f,0.f,0.f};  // lingvo: max clamped at 0
    float lrow[4] = {1.f,1.f,1.f,1.f};  // phantom exp(-max) term

    // prefetch tile kt=0
    half8 kreg[4], vreg[4];
    for (int p=0;p<4;++p){
      kreg[p] = *(const half8*)(kTb + (size_t)(p*16 + krow)*128 + kch*8);
      vreg[p] = *(const half8*)(vTb + (size_t)(p*32 + vrow)*2048 + vch*8);
    }

    for (int kt = 0; kt <= qt; ++kt){
      const int kbase = kt*64;
      __syncthreads();   // prior kt (or prior half) LDS reads complete
      for (int p=0;p<4;++p){
        *(half8*)(k_lds + (p*16 + krow)*136 + kch*8) = kreg[p];
        *(half8*)(v_lds + (p*32 + vrow)*72  + vch*8) = vreg[p];
      }
      __syncthreads();
      if (kt < qt){      // prefetch next tile; latency hidden behind compute
        const int nb = kbase + 64;
        for (int p=0;p<4;++p){
          kreg[p] = *(const half8*)(kTb + (size_t)(nb + p*16 + krow)*128 + kch*8);
          vreg[p] = *(const half8*)(vTb + (size_t)(p*32 + vrow)*2048 + nb + vch*8);
        }
      }
      // S = Q K^T  (16 rows x 64 cols per wave)
      floatx4 s[4];
      for (int ni=0;ni<4;++ni){
        floatx4 a = zero4;
        for (int kc=0;kc<4;++kc){
          half8 bk = *(const half8*)(k_lds + (ni*16 + l16)*136 + kc*32 + quad*8);
          a = __builtin_amdgcn_mfma_f32_16x16x32_f16(aq[kc], bk, a, 0,0,0);
        }
        s[ni] = a;
      }
      // cap (fast tanh), mask (diag only), online lingvo softmax
      float pm[4][4];
      float tmax[4] = {-1e30f,-1e30f,-1e30f,-1e30f};
      const bool diag = (kt == qt);
      for (int ni=0;ni<4;++ni){
        int col = kbase + ni*16 + l16;
        for (int r=0;r<4;++r){
          // 50*tanh(s/50) = 50 - 100/(exp(s*0.04)+1)
          float e = __expf(s[ni][r] * 0.04f);
          float x = 50.f - 100.f * __builtin_amdgcn_rcpf(e + 1.f);
          if (diag){
            int row = q0 + wave*16 + quad*4 + r;
            if (col > row) x = -1e30f;
          }
          pm[ni][r] = x;
          tmax[r] = fmaxf(tmax[r], x);
        }
      }
      for (int r=0;r<4;++r)
        for (int off=1; off<16; off<<=1)
          tmax[r] = fmaxf(tmax[r], __shfl_xor(tmax[r], off, 16));
      float alpha[4], mnew[4], rsum[4];
      for (int r=0;r<4;++r){
        mnew[r] = fmaxf(mrow[r], tmax[r]);
        alpha[r] = __expf(mrow[r] - mnew[r]);
        mrow[r] = mnew[r];
        rsum[r] = 0.f;
      }
      for (int ni=0;ni<4;++ni)
        for (int r=0;r<4;++r){
          float p = __expf(pm[ni][r] - mnew[r]);
          pm[ni][r] = p;
          rsum[r] += p;
        }
      for (int r=0;r<4;++r){
        for (int off=1; off<16; off<<=1) rsum[r] += __shfl_xor(rsum[r], off, 16);
        lrow[r] = alpha[r]*lrow[r] + rsum[r];
      }
      for (int nt=0;nt<8;++nt)
        for (int r=0;r<4;++r) acc_o[nt][r] *= alpha[r];
      // P: C-layout -> A-layout via wave-private LDS (m120 pattern)
      h16* pw = p_lds + wave*16*72;
      for (int ni=0;ni<4;++ni)
        for (int r=0;r<4;++r)
          pw[(quad*4+r)*72 + ni*16 + l16] = f2h(pm[ni][r]);
      __builtin_amdgcn_wave_barrier();
      half8 ap0 = *(const half8*)(pw + l16*72 + quad*8);
      half8 ap1 = *(const half8*)(pw + l16*72 + 32 + quad*8);
      for (int nt=0;nt<8;++nt){
        half8 bv0 = *(const half8*)(v_lds + (nt*16 + l16)*72 + quad*8);
        half8 bv1 = *(const half8*)(v_lds + (nt*16 + l16)*72 + 32 + quad*8);
        acc_o[nt] = __builtin_amdgcn_mfma_f32_16x16x32_f16(ap0, bv0, acc_o[nt], 0,0,0);
        acc_o[nt] = __builtin_amdgcn_mfma_f32_16x16x32_f16(ap1, bv1, acc_o[nt], 0,0,0);
      }
    }
    float invl[4];
    for (int r=0;r<4;++r) invl[r] = 1.0f / lrow[r];
    for (int nt=0;nt<8;++nt)
      for (int r=0;r<4;++r){
        int row = q0 + wave*16 + quad*4 + r;
        int col = h*128 + nt*16 + l16;
        O[((size_t)b*2048 + row)*2048 + col] = f2h(acc_o[nt][r] * invl[r]);
      }
  }
}

extern "C" void kernel_launch(void* const* d_in, const int* in_sizes, int n_in,
                              void* d_out, int out_size, void* d_ws, size_t ws_size,
                              hipStream_t stream){
  (void)in_sizes; (void)n_in; (void)out_size; (void)ws_size;
  const float* hs = (const float*)d_in[0];
  const float* wq = (const float*)d_in[1];
  const float* wk = (const float*)d_in[2];
  const float* wv = (const float*)d_in[3];
  const float* wo = (const float*)d_in[4];

  char* ws = (char*)d_ws;
  size_t off = 0;
  h16* hs_f   = (h16*)(ws + off); off += (size_t)4096*2048*2;
  h16* wqkv_t = (h16*)(ws + off); off += (size_t)6144*2048*2;
  h16* wo_t   = (h16*)(ws + off); off += (size_t)2048*2048*2;
  h16* qkv    = (h16*)(ws + off); off += (size_t)4096*6144*2;
  h16* qT     = (h16*)(ws + off); off += (size_t)4096*2048*2;
  h16* kT     = (h16*)(ws + off); off += (size_t)4096*2048*2;
  h16* vT     = (h16*)(ws + off); off += (size_t)4096*2048*2;
  h16* obuf   = qkv;  // qkv dead after rotary_split; reuse as O buffer

  hs_to_f16<<<dim3(4096), 256, 0, stream>>>(hs, hs_f, 4096*2048/8);
  wtrans<<<dim3(64,64,4), 256, 0, stream>>>(wq, wk, wv, wo, wqkv_t, wo_t);
  gemm_bt<false><<<dim3(48,32), 256, 0, stream>>>(hs_f, wqkv_t, (void*)qkv, 4096, 6144, 2048);
  rotary_split<<<dim3(32,32), 256, 0, stream>>>(qkv, qT, kT, vT);
  flash_attn<<<dim3(16,16,2), 256, 0, stream>>>(qT, kT, vT, obuf);
  gemm_bt<true><<<dim3(16,32), 256, 0, stream>>>(obuf, wo_t, d_out, 4096, 2048, 2048);
}

// Round 5
// 419.004 us; speedup vs baseline: 1.4032x; 1.1400x over previous
//
#include <hip/hip_runtime.h>

typedef _Float16 h16;
typedef __attribute__((ext_vector_type(8))) _Float16 half8;
typedef __attribute__((ext_vector_type(4))) float floatx4;

__device__ __forceinline__ h16 f2h(float f){ return (h16)f; }
__device__ __forceinline__ float h2f(h16 s){ return (float)s; }

#define GL2LDS(gp, lp) __builtin_amdgcn_global_load_lds( \
    (const __attribute__((address_space(1))) void*)(gp), \
    (__attribute__((address_space(3))) void*)(lp), 16, 0, 0)

// ---------------- f32 -> f16 convert (8 elements/thread) ----------------
__global__ __launch_bounds__(256) void hs_to_f16(const float* __restrict__ in,
                                                 h16* __restrict__ out, int n8){
  int i = blockIdx.x * 256 + threadIdx.x;
  if (i >= n8) return;
  floatx4 a = ((const floatx4*)in)[2*i];
  floatx4 b = ((const floatx4*)in)[2*i+1];
  half8 o;
  o[0]=f2h(a[0]); o[1]=f2h(a[1]); o[2]=f2h(a[2]); o[3]=f2h(a[3]);
  o[4]=f2h(b[0]); o[5]=f2h(b[1]); o[6]=f2h(b[2]); o[7]=f2h(b[3]);
  ((half8*)out)[i] = o;
}

// ------- weight transpose: dst[n][k] = src[k][n], f32 -> f16 ------------
__global__ __launch_bounds__(256) void wtrans(const float* __restrict__ wq,
                                              const float* __restrict__ wk,
                                              const float* __restrict__ wv,
                                              const float* __restrict__ wo,
                                              h16* __restrict__ wqkv_t,
                                              h16* __restrict__ wo_t){
  __shared__ float tile[32][33];
  int z = blockIdx.z;
  const float* src = (z==0)? wq : (z==1)? wk : (z==2)? wv : wo;
  h16* dst = (z<3) ? (wqkv_t + (size_t)z*2048*2048) : wo_t;
  int r0 = blockIdx.y*32, c0 = blockIdx.x*32;
  int t = threadIdx.x;
  int tr = t>>5, tc = t&31;               // 8 rows x 32 cols per pass
  for (int p=0;p<4;++p)
    tile[p*8+tr][tc] = src[(size_t)(r0+p*8+tr)*2048 + c0 + tc];
  __syncthreads();
  for (int p=0;p<4;++p)
    dst[(size_t)(c0+p*8+tr)*2048 + r0 + tc] = f2h(tile[tc][p*8+tr]);
}

// ---- fused QKV GEMM + rotary + head-split + V-transpose -----------------
// C = hs_f16 * wqkv_t^T ; 128x128 tile, BK=32, m97 staging.
// Epilogue: acc -> LDS tile (stride 130) -> rotary (Q/K) or transpose (V)
// -> qT/kT [bh][s][128] / vT [bh][128][s], all f16.
__global__ __launch_bounds__(256) void gemm_qkv(const h16* __restrict__ A,
                                                const h16* __restrict__ Bt,
                                                h16* __restrict__ qT,
                                                h16* __restrict__ kT,
                                                h16* __restrict__ vT){
  const int K = 2048;
  __shared__ h16 smem[128*130];   // 33.3 KB: staging (16 KB) U epilogue tile
  h16* a_lds = smem;              // 128*32
  h16* b_lds = smem + 4096;       // 128*32
  const int t = threadIdx.x;
  const int m0 = blockIdx.y * 128, n0 = blockIdx.x * 128;
  const int wave = t >> 6, lane = t & 63, quad = lane >> 4, l16 = lane & 15;
  const int wm = (wave & 1) * 64, wn = (wave >> 1) * 64;
  const int srow = wave*16 + (lane >> 2);
  const int schunk = lane & 3;
  const h16* Abase = A  + (size_t)(m0 + srow)*K + schunk*8;
  const h16* Bbase = Bt + (size_t)(n0 + srow)*K + schunk*8;
  h16* aL = a_lds + wave*512;
  h16* bL = b_lds + wave*512;

  floatx4 zero4 = {0.f,0.f,0.f,0.f};
  floatx4 acc[4][4];
  for (int mi=0;mi<4;++mi) for (int ni=0;ni<4;++ni) acc[mi][ni] = zero4;

  for (int k0 = 0; k0 < K; k0 += 32){
    GL2LDS(Abase + k0,              aL);
    GL2LDS(Abase + (size_t)64*K+k0, aL + 2048);
    GL2LDS(Bbase + k0,              bL);
    GL2LDS(Bbase + (size_t)64*K+k0, bL + 2048);
    __syncthreads();
    half8 af[4], bfr[4];
    for (int mi=0;mi<4;++mi) af[mi]  = *(const half8*)(a_lds + (wm + mi*16 + l16)*32 + quad*8);
    for (int ni=0;ni<4;++ni) bfr[ni] = *(const half8*)(b_lds + (wn + ni*16 + l16)*32 + quad*8);
    for (int mi=0;mi<4;++mi)
      for (int ni=0;ni<4;++ni)
        acc[mi][ni] = __builtin_amdgcn_mfma_f32_16x16x32_f16(af[mi], bfr[ni], acc[mi][ni], 0,0,0);
    __syncthreads();
  }
  // ---- epilogue: stage tile to LDS (stride 130 f16) ----
  for (int mi=0;mi<4;++mi)
    for (int ni=0;ni<4;++ni)
      for (int r=0;r<4;++r)
        smem[(wm + mi*16 + quad*4 + r)*130 + wn + ni*16 + l16] = f2h(acc[mi][ni][r]);
  __syncthreads();
  const int sec = n0 >> 11;           // 0=Q, 1=K, 2=V
  const int hh  = (n0 & 2047) >> 7;
  const int bb  = m0 >> 11;
  const int s0g = m0 & 2047;
  const int bhg = bb*16 + hh;
  if (sec < 2){
    h16* dst = sec ? kT : qT;
    const int d = t & 63;
    const int g = t >> 6;
    const float inv = __expf(-0.14391157f * (float)d);   // ln(10000)/64
    for (int p=0;p<32;++p){
      int sr = p*4 + g;                 // wave-uniform row -> contiguous LDS read
      int s  = s0g + sr;
      float sn, cs; __sincosf((float)s * inv, &sn, &cs);
      float x1 = h2f(smem[sr*130 + d]);
      float x2 = h2f(smem[sr*130 + d + 64]);
      size_t o = ((size_t)bhg*2048 + s)*128 + d;
      dst[o]      = f2h(x1*cs - x2*sn);
      dst[o + 64] = f2h(x2*cs + x1*sn);
    }
  } else {
    const int sr = t & 127;             // lane = s -> stride 65 words: conflict-free
    const int g  = t >> 7;
    for (int p=0;p<64;++p){
      int d = p*2 + g;
      vT[((size_t)bhg*128 + d)*2048 + s0g + sr] = smem[sr*130 + d];
    }
  }
}

// ---------------- O-projection GEMM: f32 out ----------------------------
__global__ __launch_bounds__(256) void gemm_out(const h16* __restrict__ A,
                                                const h16* __restrict__ Bt,
                                                float* __restrict__ Cout){
  const int K = 2048, N = 2048;
  __shared__ h16 a_lds[128*32];
  __shared__ h16 b_lds[128*32];
  const int t = threadIdx.x;
  const int m0 = blockIdx.y * 128, n0 = blockIdx.x * 128;
  const int wave = t >> 6, lane = t & 63, quad = lane >> 4, l16 = lane & 15;
  const int wm = (wave & 1) * 64, wn = (wave >> 1) * 64;
  const int srow = wave*16 + (lane >> 2);
  const int schunk = lane & 3;
  const h16* Abase = A  + (size_t)(m0 + srow)*K + schunk*8;
  const h16* Bbase = Bt + (size_t)(n0 + srow)*K + schunk*8;
  h16* aL = a_lds + wave*512;
  h16* bL = b_lds + wave*512;

  floatx4 zero4 = {0.f,0.f,0.f,0.f};
  floatx4 acc[4][4];
  for (int mi=0;mi<4;++mi) for (int ni=0;ni<4;++ni) acc[mi][ni] = zero4;

  for (int k0 = 0; k0 < K; k0 += 32){
    GL2LDS(Abase + k0,              aL);
    GL2LDS(Abase + (size_t)64*K+k0, aL + 2048);
    GL2LDS(Bbase + k0,              bL);
    GL2LDS(Bbase + (size_t)64*K+k0, bL + 2048);
    __syncthreads();
    half8 af[4], bfr[4];
    for (int mi=0;mi<4;++mi) af[mi]  = *(const half8*)(a_lds + (wm + mi*16 + l16)*32 + quad*8);
    for (int ni=0;ni<4;++ni) bfr[ni] = *(const half8*)(b_lds + (wn + ni*16 + l16)*32 + quad*8);
    for (int mi=0;mi<4;++mi)
      for (int ni=0;ni<4;++ni)
        acc[mi][ni] = __builtin_amdgcn_mfma_f32_16x16x32_f16(af[mi], bfr[ni], acc[mi][ni], 0,0,0);
    __syncthreads();
  }
  for (int mi=0;mi<4;++mi)
    for (int ni=0;ni<4;++ni)
      for (int r=0;r<4;++r){
        int row = m0 + wm + mi*16 + quad*4 + r;
        int col = n0 + wn + ni*16 + l16;
        Cout[(size_t)row*N + col] = acc[mi][ni][r];
      }
}

// ---------------- flash attention (lingvo softmax + tanh cap) ------------
// grid (16, h, b); block pairs q-tiles {x, 31-x} -> 33 kt per block (balanced).
__global__ __launch_bounds__(256) void flash_attn(const h16* __restrict__ qT,
                                                  const h16* __restrict__ kT,
                                                  const h16* __restrict__ vT,
                                                  h16* __restrict__ O){
  __shared__ h16 k_lds[64*136];    // [kn][kd], pad 128 -> 136
  __shared__ h16 v_lds[128*72];    // [d][s],  pad 64 -> 72
  __shared__ h16 p_lds[4*16*72];   // per-wave 16 x 64 (pad 72)
  const int t = threadIdx.x, wave = t>>6, lane = t&63, quad = lane>>4, l16 = lane&15;
  const int h = blockIdx.y, b = blockIdx.z;
  const int bh = b*16 + h;
  const int krow = t>>4, kch = t&15;
  const int vrow = t>>3, vch = t&7;
  const h16* kTb = kT + (size_t)bh*2048*128;
  const h16* vTb = vT + (size_t)bh*128*2048;
  floatx4 zero4 = {0.f,0.f,0.f,0.f};

  for (int half = 0; half < 2; ++half){
    const int qt = half ? 31 - (int)blockIdx.x : (int)blockIdx.x;
    const int q0 = qt*64;
    const size_t qrow = (size_t)bh*2048 + q0 + wave*16 + l16;
    half8 aq[4];
    for (int kc=0;kc<4;++kc) aq[kc] = *(const half8*)(qT + qrow*128 + kc*32 + quad*8);
    floatx4 acc_o[8];
    for (int nt=0;nt<8;++nt) acc_o[nt] = zero4;
    float mrow[4] = {0.f,0.f,0.f,0.f};  // lingvo: max clamped at 0
    float lrow[4] = {1.f,1.f,1.f,1.f};  // phantom exp(-max) term

    half8 kreg[4], vreg[4];
    for (int p=0;p<4;++p){
      kreg[p] = *(const half8*)(kTb + (size_t)(p*16 + krow)*128 + kch*8);
      vreg[p] = *(const half8*)(vTb + (size_t)(p*32 + vrow)*2048 + vch*8);
    }

    for (int kt = 0; kt <= qt; ++kt){
      const int kbase = kt*64;
      __syncthreads();
      for (int p=0;p<4;++p){
        *(half8*)(k_lds + (p*16 + krow)*136 + kch*8) = kreg[p];
        *(half8*)(v_lds + (p*32 + vrow)*72  + vch*8) = vreg[p];
      }
      __syncthreads();
      if (kt < qt){
        const int nb = kbase + 64;
        for (int p=0;p<4;++p){
          kreg[p] = *(const half8*)(kTb + (size_t)(nb + p*16 + krow)*128 + kch*8);
          vreg[p] = *(const half8*)(vTb + (size_t)(p*32 + vrow)*2048 + nb + vch*8);
        }
      }
      floatx4 s[4];
      for (int ni=0;ni<4;++ni){
        floatx4 a = zero4;
        for (int kc=0;kc<4;++kc){
          half8 bk = *(const half8*)(k_lds + (ni*16 + l16)*136 + kc*32 + quad*8);
          a = __builtin_amdgcn_mfma_f32_16x16x32_f16(aq[kc], bk, a, 0,0,0);
        }
        s[ni] = a;
      }
      float pm[4][4];
      float tmax[4] = {-1e30f,-1e30f,-1e30f,-1e30f};
      const bool diag = (kt == qt);
      for (int ni=0;ni<4;++ni){
        int col = kbase + ni*16 + l16;
        for (int r=0;r<4;++r){
          float e = __expf(s[ni][r] * 0.04f);          // 50*tanh(x/50)
          float x = 50.f - 100.f * __builtin_amdgcn_rcpf(e + 1.f);
          if (diag){
            int row = q0 + wave*16 + quad*4 + r;
            if (col > row) x = -1e30f;
          }
          pm[ni][r] = x;
          tmax[r] = fmaxf(tmax[r], x);
        }
      }
      for (int r=0;r<4;++r)
        for (int off=1; off<16; off<<=1)
          tmax[r] = fmaxf(tmax[r], __shfl_xor(tmax[r], off, 16));
      float alpha[4], mnew[4], rsum[4];
      for (int r=0;r<4;++r){
        mnew[r] = fmaxf(mrow[r], tmax[r]);
        alpha[r] = __expf(mrow[r] - mnew[r]);
        mrow[r] = mnew[r];
        rsum[r] = 0.f;
      }
      for (int ni=0;ni<4;++ni)
        for (int r=0;r<4;++r){
          float p = __expf(pm[ni][r] - mnew[r]);
          pm[ni][r] = p;
          rsum[r] += p;
        }
      for (int r=0;r<4;++r){
        for (int off=1; off<16; off<<=1) rsum[r] += __shfl_xor(rsum[r], off, 16);
        lrow[r] = alpha[r]*lrow[r] + rsum[r];
      }
      for (int nt=0;nt<8;++nt)
        for (int r=0;r<4;++r) acc_o[nt][r] *= alpha[r];
      h16* pw = p_lds + wave*16*72;
      for (int ni=0;ni<4;++ni)
        for (int r=0;r<4;++r)
          pw[(quad*4+r)*72 + ni*16 + l16] = f2h(pm[ni][r]);
      __builtin_amdgcn_wave_barrier();
      half8 ap0 = *(const half8*)(pw + l16*72 + quad*8);
      half8 ap1 = *(const half8*)(pw + l16*72 + 32 + quad*8);
      for (int nt=0;nt<8;++nt){
        half8 bv0 = *(const half8*)(v_lds + (nt*16 + l16)*72 + quad*8);
        half8 bv1 = *(const half8*)(v_lds + (nt*16 + l16)*72 + 32 + quad*8);
        acc_o[nt] = __builtin_amdgcn_mfma_f32_16x16x32_f16(ap0, bv0, acc_o[nt], 0,0,0);
        acc_o[nt] = __builtin_amdgcn_mfma_f32_16x16x32_f16(ap1, bv1, acc_o[nt], 0,0,0);
      }
    }
    float invl[4];
    for (int r=0;r<4;++r) invl[r] = 1.0f / lrow[r];
    for (int nt=0;nt<8;++nt)
      for (int r=0;r<4;++r){
        int row = q0 + wave*16 + quad*4 + r;
        int col = h*128 + nt*16 + l16;
        O[((size_t)b*2048 + row)*2048 + col] = f2h(acc_o[nt][r] * invl[r]);
      }
  }
}

extern "C" void kernel_launch(void* const* d_in, const int* in_sizes, int n_in,
                              void* d_out, int out_size, void* d_ws, size_t ws_size,
                              hipStream_t stream){
  (void)in_sizes; (void)n_in; (void)out_size; (void)ws_size;
  const float* hs = (const float*)d_in[0];
  const float* wq = (const float*)d_in[1];
  const float* wk = (const float*)d_in[2];
  const float* wv = (const float*)d_in[3];
  const float* wo = (const float*)d_in[4];

  char* ws = (char*)d_ws;
  size_t off = 0;
  h16* hs_f   = (h16*)(ws + off); off += (size_t)4096*2048*2;
  h16* wqkv_t = (h16*)(ws + off); off += (size_t)6144*2048*2;
  h16* wo_t   = (h16*)(ws + off); off += (size_t)2048*2048*2;
  h16* qT     = (h16*)(ws + off); off += (size_t)4096*2048*2;
  h16* kT     = (h16*)(ws + off); off += (size_t)4096*2048*2;
  h16* vT     = (h16*)(ws + off); off += (size_t)4096*2048*2;
  h16* obuf   = (h16*)(ws + off); off += (size_t)4096*2048*2;

  hs_to_f16<<<dim3(4096), 256, 0, stream>>>(hs, hs_f, 4096*2048/8);
  wtrans<<<dim3(64,64,4), 256, 0, stream>>>(wq, wk, wv, wo, wqkv_t, wo_t);
  gemm_qkv<<<dim3(48,32), 256, 0, stream>>>(hs_f, wqkv_t, qT, kT, vT);
  flash_attn<<<dim3(16,16,2), 256, 0, stream>>>(qT, kT, vT, obuf);
  gemm_out<<<dim3(16,32), 256, 0, stream>>>(obuf, wo_t, (float*)d_out);
}

// Round 6
// 395.448 us; speedup vs baseline: 1.4867x; 1.0596x over previous
//
#include <hip/hip_runtime.h>

typedef _Float16 h16;
typedef __attribute__((ext_vector_type(8))) _Float16 half8;
typedef __attribute__((ext_vector_type(4))) float floatx4;

__device__ __forceinline__ h16 f2h(float f){ return (h16)f; }
__device__ __forceinline__ float h2f(h16 s){ return (float)s; }

#define GL2LDS(gp, lp) __builtin_amdgcn_global_load_lds( \
    (const __attribute__((address_space(1))) void*)(gp), \
    (__attribute__((address_space(3))) void*)(lp), 16, 0, 0)

// ---- prep: z<4 -> weight transpose f32->f16 ; z==4 -> hs f32->f16 -------
__global__ __launch_bounds__(256) void prep(const float* __restrict__ wq,
                                            const float* __restrict__ wk,
                                            const float* __restrict__ wv,
                                            const float* __restrict__ wo,
                                            const float* __restrict__ hs,
                                            h16* __restrict__ wqkv_t,
                                            h16* __restrict__ wo_t,
                                            h16* __restrict__ hs_f){
  __shared__ float tile[32][33];
  int z = blockIdx.z;
  int t = threadIdx.x;
  if (z == 4){
    int i = ((int)blockIdx.y*64 + (int)blockIdx.x)*256 + t;   // 4096 blocks
    floatx4 a = ((const floatx4*)hs)[2*i];
    floatx4 b = ((const floatx4*)hs)[2*i+1];
    half8 o;
    o[0]=f2h(a[0]); o[1]=f2h(a[1]); o[2]=f2h(a[2]); o[3]=f2h(a[3]);
    o[4]=f2h(b[0]); o[5]=f2h(b[1]); o[6]=f2h(b[2]); o[7]=f2h(b[3]);
    ((half8*)hs_f)[i] = o;
    return;
  }
  const float* src = (z==0)? wq : (z==1)? wk : (z==2)? wv : wo;
  h16* dst = (z<3) ? (wqkv_t + (size_t)z*2048*2048) : wo_t;
  int r0 = blockIdx.y*32, c0 = blockIdx.x*32;
  int tr = t>>5, tc = t&31;
  for (int p=0;p<4;++p)
    tile[p*8+tr][tc] = src[(size_t)(r0+p*8+tr)*2048 + c0 + tc];
  __syncthreads();
  for (int p=0;p<4;++p)
    dst[(size_t)(c0+p*8+tr)*2048 + r0 + tc] = f2h(tile[tc][p*8+tr]);
}

// ---- fused QKV GEMM + rotary + head-split + V-transpose -----------------
// 128x128 tile, BK=64, XOR-swizzled GL2LDS staging (chunk g of row R at
// slot g^(R&7): writer lane-contiguous, reader 2-way-bank free).
__global__ __launch_bounds__(256) void gemm_qkv(const h16* __restrict__ A,
                                                const h16* __restrict__ Bt,
                                                h16* __restrict__ qT,
                                                h16* __restrict__ kT,
                                                h16* __restrict__ vT){
  const int K = 2048;
  __shared__ h16 smem[128*130];   // 33.3 KB: staging (32 KB) U epilogue tile
  h16* a_lds = smem;              // 128*64
  h16* b_lds = smem + 8192;       // 128*64
  const int t = threadIdx.x;
  const int m0 = blockIdx.y * 128, n0 = blockIdx.x * 128;
  const int wave = t >> 6, lane = t & 63, quad = lane >> 4, l16 = lane & 15;
  const int wm = (wave & 1) * 64, wn = (wave >> 1) * 64;
  const int l3 = lane >> 3, c7 = lane & 7;
  const int xorc = c7 ^ l3;                    // global 16B chunk for this lane
  const h16* Ab = A  + (size_t)(m0 + wave*8 + l3)*K + xorc*8;
  const h16* Bb = Bt + (size_t)(n0 + wave*8 + l3)*K + xorc*8;
  h16* aL = a_lds + wave*512;
  h16* bL = b_lds + wave*512;

  floatx4 zero4 = {0.f,0.f,0.f,0.f};
  floatx4 acc[4][4];
  for (int mi=0;mi<4;++mi) for (int ni=0;ni<4;++ni) acc[mi][ni] = zero4;

  for (int k0 = 0; k0 < K; k0 += 64){
    for (int p=0;p<4;++p){
      GL2LDS(Ab + (size_t)p*32*K + k0, aL + p*2048);
      GL2LDS(Bb + (size_t)p*32*K + k0, bL + p*2048);
    }
    __syncthreads();
    for (int kk=0; kk<2; ++kk){
      const int s0 = ((kk*4 + quad) ^ (l16 & 7)) * 8;
      half8 af[4], bfr[4];
      for (int mi=0;mi<4;++mi) af[mi]  = *(const half8*)(a_lds + (wm + mi*16 + l16)*64 + s0);
      for (int ni=0;ni<4;++ni) bfr[ni] = *(const half8*)(b_lds + (wn + ni*16 + l16)*64 + s0);
      for (int mi=0;mi<4;++mi)
        for (int ni=0;ni<4;++ni)
          acc[mi][ni] = __builtin_amdgcn_mfma_f32_16x16x32_f16(af[mi], bfr[ni], acc[mi][ni], 0,0,0);
    }
    __syncthreads();
  }
  // ---- epilogue: stage tile to LDS (stride 130 f16) ----
  for (int mi=0;mi<4;++mi)
    for (int ni=0;ni<4;++ni)
      for (int r=0;r<4;++r)
        smem[(wm + mi*16 + quad*4 + r)*130 + wn + ni*16 + l16] = f2h(acc[mi][ni][r]);
  __syncthreads();
  const int sec = n0 >> 11;           // 0=Q, 1=K, 2=V
  const int hh  = (n0 & 2047) >> 7;
  const int bb  = m0 >> 11;
  const int s0g = m0 & 2047;
  const int bhg = bb*16 + hh;
  if (sec < 2){
    h16* dst = sec ? kT : qT;
    const int d = t & 63;
    const int g = t >> 6;
    const float inv = __expf(-0.14391157f * (float)d);   // ln(10000)/64
    for (int p=0;p<32;++p){
      int sr = p*4 + g;
      int s  = s0g + sr;
      float sn, cs; __sincosf((float)s * inv, &sn, &cs);
      float x1 = h2f(smem[sr*130 + d]);
      float x2 = h2f(smem[sr*130 + d + 64]);
      size_t o = ((size_t)bhg*2048 + s)*128 + d;
      dst[o]      = f2h(x1*cs - x2*sn);
      dst[o + 64] = f2h(x2*cs + x1*sn);
    }
  } else {
    const int sr = t & 127;             // lane = s -> stride 65 words: conflict-free
    const int g  = t >> 7;
    for (int p=0;p<64;++p){
      int d = p*2 + g;
      vT[((size_t)bhg*128 + d)*2048 + s0g + sr] = smem[sr*130 + d];
    }
  }
}

// ---------------- O-projection GEMM: f32 out (BK=64 swizzled) ------------
__global__ __launch_bounds__(256) void gemm_out(const h16* __restrict__ A,
                                                const h16* __restrict__ Bt,
                                                float* __restrict__ Cout){
  const int K = 2048, N = 2048;
  __shared__ h16 a_lds[128*64];
  __shared__ h16 b_lds[128*64];
  const int t = threadIdx.x;
  const int m0 = blockIdx.y * 128, n0 = blockIdx.x * 128;
  const int wave = t >> 6, lane = t & 63, quad = lane >> 4, l16 = lane & 15;
  const int wm = (wave & 1) * 64, wn = (wave >> 1) * 64;
  const int l3 = lane >> 3, c7 = lane & 7;
  const int xorc = c7 ^ l3;
  const h16* Ab = A  + (size_t)(m0 + wave*8 + l3)*K + xorc*8;
  const h16* Bb = Bt + (size_t)(n0 + wave*8 + l3)*K + xorc*8;
  h16* aL = a_lds + wave*512;
  h16* bL = b_lds + wave*512;

  floatx4 zero4 = {0.f,0.f,0.f,0.f};
  floatx4 acc[4][4];
  for (int mi=0;mi<4;++mi) for (int ni=0;ni<4;++ni) acc[mi][ni] = zero4;

  for (int k0 = 0; k0 < K; k0 += 64){
    for (int p=0;p<4;++p){
      GL2LDS(Ab + (size_t)p*32*K + k0, aL + p*2048);
      GL2LDS(Bb + (size_t)p*32*K + k0, bL + p*2048);
    }
    __syncthreads();
    for (int kk=0; kk<2; ++kk){
      const int s0 = ((kk*4 + quad) ^ (l16 & 7)) * 8;
      half8 af[4], bfr[4];
      for (int mi=0;mi<4;++mi) af[mi]  = *(const half8*)(a_lds + (wm + mi*16 + l16)*64 + s0);
      for (int ni=0;ni<4;++ni) bfr[ni] = *(const half8*)(b_lds + (wn + ni*16 + l16)*64 + s0);
      for (int mi=0;mi<4;++mi)
        for (int ni=0;ni<4;++ni)
          acc[mi][ni] = __builtin_amdgcn_mfma_f32_16x16x32_f16(af[mi], bfr[ni], acc[mi][ni], 0,0,0);
    }
    __syncthreads();
  }
  for (int mi=0;mi<4;++mi)
    for (int ni=0;ni<4;++ni)
      for (int r=0;r<4;++r){
        int row = m0 + wm + mi*16 + quad*4 + r;
        int col = n0 + wn + ni*16 + l16;
        Cout[(size_t)row*N + col] = acc[mi][ni][r];
      }
}

// ---------------- flash attention (lingvo softmax + tanh cap) ------------
// grid (16, h, b); block pairs q-tiles {x, 31-x} -> 33 kt per block.
// Row-sum via MFMA ones-columns (v_lds rows 128..143 = 1.0) -> no rsum shuffle.
__global__ __launch_bounds__(256) void flash_attn(const h16* __restrict__ qT,
                                                  const h16* __restrict__ kT,
                                                  const h16* __restrict__ vT,
                                                  h16* __restrict__ O){
  __shared__ h16 k_lds[64*136];    // [kn][kd], pad 128 -> 136
  __shared__ h16 v_lds[144*72];    // [d][s], rows 128..143 = ones
  __shared__ h16 p_lds[4*16*72];   // per-wave 16 x 64 (pad 72)
  const int t = threadIdx.x, wave = t>>6, lane = t&63, quad = lane>>4, l16 = lane&15;
  const int h = blockIdx.y, b = blockIdx.z;
  const int bh = b*16 + h;
  const int krow = t>>4, kch = t&15;
  const int vrow = t>>3, vch = t&7;
  const h16* kTb = kT + (size_t)bh*2048*128;
  const h16* vTb = vT + (size_t)bh*128*2048;
  floatx4 zero4 = {0.f,0.f,0.f,0.f};
  // ones rows for the row-sum trick (persist across iterations)
  for (int i = t; i < 16*64; i += 256)
    v_lds[(128 + (i>>6))*72 + (i&63)] = (h16)1.0f;
  __syncthreads();

  for (int half = 0; half < 2; ++half){
    const int qt = half ? 31 - (int)blockIdx.x : (int)blockIdx.x;
    const int q0 = qt*64;
    const size_t qrow = (size_t)bh*2048 + q0 + wave*16 + l16;
    half8 aq[4];
    for (int kc=0;kc<4;++kc) aq[kc] = *(const half8*)(qT + qrow*128 + kc*32 + quad*8);
    floatx4 acc_o[8];
    for (int nt=0;nt<8;++nt) acc_o[nt] = zero4;
    floatx4 acc_l = zero4;              // row-sum accumulator (every col = rowsum)
    float mrow[4] = {0.f,0.f,0.f,0.f};  // lingvo: max clamped at 0

    half8 kreg[4], vreg[4];
    for (int p=0;p<4;++p){
      kreg[p] = *(const half8*)(kTb + (size_t)(p*16 + krow)*128 + kch*8);
      vreg[p] = *(const half8*)(vTb + (size_t)(p*32 + vrow)*2048 + vch*8);
    }

    for (int kt = 0; kt <= qt; ++kt){
      const int kbase = kt*64;
      __syncthreads();
      for (int p=0;p<4;++p){
        *(half8*)(k_lds + (p*16 + krow)*136 + kch*8) = kreg[p];
        *(half8*)(v_lds + (p*32 + vrow)*72  + vch*8) = vreg[p];
      }
      __syncthreads();
      if (kt < qt){
        const int nb = kbase + 64;
        for (int p=0;p<4;++p){
          kreg[p] = *(const half8*)(kTb + (size_t)(nb + p*16 + krow)*128 + kch*8);
          vreg[p] = *(const half8*)(vTb + (size_t)(p*32 + vrow)*2048 + nb + vch*8);
        }
      }
      floatx4 s[4];
      for (int ni=0;ni<4;++ni){
        floatx4 a = zero4;
        for (int kc=0;kc<4;++kc){
          half8 bk = *(const half8*)(k_lds + (ni*16 + l16)*136 + kc*32 + quad*8);
          a = __builtin_amdgcn_mfma_f32_16x16x32_f16(aq[kc], bk, a, 0,0,0);
        }
        s[ni] = a;
      }
      float pm[4][4];
      float tmax[4] = {-1e30f,-1e30f,-1e30f,-1e30f};
      const bool diag = (kt == qt);
      for (int ni=0;ni<4;++ni){
        int col = kbase + ni*16 + l16;
        for (int r=0;r<4;++r){
          float e = __expf(s[ni][r] * 0.04f);          // 50*tanh(x/50)
          float x = 50.f - 100.f * __builtin_amdgcn_rcpf(e + 1.f);
          if (diag){
            int row = q0 + wave*16 + quad*4 + r;
            if (col > row) x = -1e30f;
          }
          pm[ni][r] = x;
          tmax[r] = fmaxf(tmax[r], x);
        }
      }
      for (int r=0;r<4;++r)
        for (int off=1; off<16; off<<=1)
          tmax[r] = fmaxf(tmax[r], __shfl_xor(tmax[r], off, 16));
      float alpha[4], mnew[4];
      for (int r=0;r<4;++r){
        mnew[r] = fmaxf(mrow[r], tmax[r]);
        alpha[r] = __expf(mrow[r] - mnew[r]);
        mrow[r] = mnew[r];
      }
      for (int ni=0;ni<4;++ni)
        for (int r=0;r<4;++r)
          pm[ni][r] = __expf(pm[ni][r] - mnew[r]);
      for (int nt=0;nt<8;++nt)
        for (int r=0;r<4;++r) acc_o[nt][r] *= alpha[r];
      for (int r=0;r<4;++r) acc_l[r] *= alpha[r];
      h16* pw = p_lds + wave*16*72;
      for (int ni=0;ni<4;++ni)
        for (int r=0;r<4;++r)
          pw[(quad*4+r)*72 + ni*16 + l16] = f2h(pm[ni][r]);
      __builtin_amdgcn_wave_barrier();
      half8 ap0 = *(const half8*)(pw + l16*72 + quad*8);
      half8 ap1 = *(const half8*)(pw + l16*72 + 32 + quad*8);
      for (int nt=0;nt<8;++nt){
        half8 bv0 = *(const half8*)(v_lds + (nt*16 + l16)*72 + quad*8);
        half8 bv1 = *(const half8*)(v_lds + (nt*16 + l16)*72 + 32 + quad*8);
        acc_o[nt] = __builtin_amdgcn_mfma_f32_16x16x32_f16(ap0, bv0, acc_o[nt], 0,0,0);
        acc_o[nt] = __builtin_amdgcn_mfma_f32_16x16x32_f16(ap1, bv1, acc_o[nt], 0,0,0);
      }
      { // row-sum: B rows 128..143 are all ones -> every lane gets rowsum
        half8 bo0 = *(const half8*)(v_lds + (128 + l16)*72 + quad*8);
        half8 bo1 = *(const half8*)(v_lds + (128 + l16)*72 + 32 + quad*8);
        acc_l = __builtin_amdgcn_mfma_f32_16x16x32_f16(ap0, bo0, acc_l, 0,0,0);
        acc_l = __builtin_amdgcn_mfma_f32_16x16x32_f16(ap1, bo1, acc_l, 0,0,0);
      }
    }
    float invl[4];
    for (int r=0;r<4;++r) invl[r] = 1.0f / (acc_l[r] + __expf(-mrow[r]));
    for (int nt=0;nt<8;++nt)
      for (int r=0;r<4;++r){
        int row = q0 + wave*16 + quad*4 + r;
        int col = h*128 + nt*16 + l16;
        O[((size_t)b*2048 + row)*2048 + col] = f2h(acc_o[nt][r] * invl[r]);
      }
  }
}

extern "C" void kernel_launch(void* const* d_in, const int* in_sizes, int n_in,
                              void* d_out, int out_size, void* d_ws, size_t ws_size,
                              hipStream_t stream){
  (void)in_sizes; (void)n_in; (void)out_size; (void)ws_size;
  const float* hs = (const float*)d_in[0];
  const float* wq = (const float*)d_in[1];
  const float* wk = (const float*)d_in[2];
  const float* wv = (const float*)d_in[3];
  const float* wo = (const float*)d_in[4];

  char* ws = (char*)d_ws;
  size_t off = 0;
  h16* hs_f   = (h16*)(ws + off); off += (size_t)4096*2048*2;
  h16* wqkv_t = (h16*)(ws + off); off += (size_t)6144*2048*2;
  h16* wo_t   = (h16*)(ws + off); off += (size_t)2048*2048*2;
  h16* qT     = (h16*)(ws + off); off += (size_t)4096*2048*2;
  h16* kT     = (h16*)(ws + off); off += (size_t)4096*2048*2;
  h16* vT     = (h16*)(ws + off); off += (size_t)4096*2048*2;
  h16* obuf   = (h16*)(ws + off); off += (size_t)4096*2048*2;

  prep<<<dim3(64,64,5), 256, 0, stream>>>(wq, wk, wv, wo, hs, wqkv_t, wo_t, hs_f);
  gemm_qkv<<<dim3(48,32), 256, 0, stream>>>(hs_f, wqkv_t, qT, kT, vT);
  flash_attn<<<dim3(16,16,2), 256, 0, stream>>>(qT, kT, vT, obuf);
  gemm_out<<<dim3(16,32), 256, 0, stream>>>(obuf, wo_t, (float*)d_out);
}

// Round 8
// 390.013 us; speedup vs baseline: 1.5075x; 1.0139x over previous
//
#include <hip/hip_runtime.h>

typedef _Float16 h16;
typedef __attribute__((ext_vector_type(4))) _Float16 half4;
typedef __attribute__((ext_vector_type(8))) _Float16 half8;
typedef __attribute__((ext_vector_type(4))) float floatx4;

__device__ __forceinline__ h16 f2h(float f){ return (h16)f; }
__device__ __forceinline__ float h2f(h16 s){ return (float)s; }

#define GL2LDS(gp, lp) __builtin_amdgcn_global_load_lds( \
    (const __attribute__((address_space(1))) void*)(gp), \
    (__attribute__((address_space(3))) void*)(lp), 16, 0, 0)

// ---- prep: z<4 -> weight transpose f32->f16 (64x64 tiles, vectorized);
//            z==4 -> hs f32->f16 (4x half8 per thread) --------------------
__global__ __launch_bounds__(256) void prep(const float* __restrict__ wq,
                                            const float* __restrict__ wk,
                                            const float* __restrict__ wv,
                                            const float* __restrict__ wo,
                                            const float* __restrict__ hs,
                                            h16* __restrict__ wqkv_t,
                                            h16* __restrict__ wo_t,
                                            h16* __restrict__ hs_f){
  __shared__ float tile[64][65];
  int z = blockIdx.z;
  int t = threadIdx.x;
  if (z == 4){
    int blk = (int)blockIdx.y*32 + (int)blockIdx.x;   // 1024 blocks
    for (int j=0;j<4;++j){
      int i = blk*1024 + j*256 + t;                   // half8 index
      floatx4 a = ((const floatx4*)hs)[2*i];
      floatx4 b = ((const floatx4*)hs)[2*i+1];
      half8 o;
      o[0]=f2h(a[0]); o[1]=f2h(a[1]); o[2]=f2h(a[2]); o[3]=f2h(a[3]);
      o[4]=f2h(b[0]); o[5]=f2h(b[1]); o[6]=f2h(b[2]); o[7]=f2h(b[3]);
      ((half8*)hs_f)[i] = o;
    }
    return;
  }
  const float* src = (z==0)? wq : (z==1)? wk : (z==2)? wv : wo;
  h16* dst = (z<3) ? (wqkv_t + (size_t)z*2048*2048) : wo_t;
  const int r0 = blockIdx.y*64, c0 = blockIdx.x*64;
  const int rr = t>>4, c4 = (t&15)*4;
  for (int p=0;p<4;++p){
    floatx4 v = *(const floatx4*)(src + (size_t)(r0+p*16+rr)*2048 + c0 + c4);
    tile[p*16+rr][c4+0]=v[0]; tile[p*16+rr][c4+1]=v[1];
    tile[p*16+rr][c4+2]=v[2]; tile[p*16+rr][c4+3]=v[3];
  }
  __syncthreads();
  const int rc = t&15;
  for (int p=0;p<4;++p){
    int cdst = (t>>4) + p*16;
    half4 o;
    o[0]=f2h(tile[rc*4+0][cdst]); o[1]=f2h(tile[rc*4+1][cdst]);
    o[2]=f2h(tile[rc*4+2][cdst]); o[3]=f2h(tile[rc*4+3][cdst]);
    *(half4*)(dst + (size_t)(c0+cdst)*2048 + r0 + rc*4) = o;
  }
}

// ---- fused QKV GEMM + rotary + head-split + V-transpose -----------------
// 128x128 tile, BK=64, XOR-swizzled GL2LDS staging.
__global__ __launch_bounds__(256) void gemm_qkv(const h16* __restrict__ A,
                                                const h16* __restrict__ Bt,
                                                h16* __restrict__ qT,
                                                h16* __restrict__ kT,
                                                h16* __restrict__ vT){
  const int K = 2048;
  __shared__ h16 smem[128*130];   // 33.3 KB: staging (32 KB) U epilogue tile
  h16* a_lds = smem;              // 128*64
  h16* b_lds = smem + 8192;       // 128*64
  const int t = threadIdx.x;
  const int m0 = blockIdx.y * 128, n0 = blockIdx.x * 128;
  const int wave = t >> 6, lane = t & 63, quad = lane >> 4, l16 = lane & 15;
  const int wm = (wave & 1) * 64, wn = (wave >> 1) * 64;
  const int l3 = lane >> 3, c7 = lane & 7;
  const int xorc = c7 ^ l3;                    // global 16B chunk for this lane
  const h16* Ab = A  + (size_t)(m0 + wave*8 + l3)*K + xorc*8;
  const h16* Bb = Bt + (size_t)(n0 + wave*8 + l3)*K + xorc*8;
  h16* aL = a_lds + wave*512;
  h16* bL = b_lds + wave*512;

  floatx4 zero4 = {0.f,0.f,0.f,0.f};
  floatx4 acc[4][4];
  for (int mi=0;mi<4;++mi) for (int ni=0;ni<4;++ni) acc[mi][ni] = zero4;

  for (int k0 = 0; k0 < K; k0 += 64){
    for (int p=0;p<4;++p){
      GL2LDS(Ab + (size_t)p*32*K + k0, aL + p*2048);
      GL2LDS(Bb + (size_t)p*32*K + k0, bL + p*2048);
    }
    __syncthreads();
    for (int kk=0; kk<2; ++kk){
      const int s0 = ((kk*4 + quad) ^ (l16 & 7)) * 8;
      half8 af[4], bfr[4];
      for (int mi=0;mi<4;++mi) af[mi]  = *(const half8*)(a_lds + (wm + mi*16 + l16)*64 + s0);
      for (int ni=0;ni<4;++ni) bfr[ni] = *(const half8*)(b_lds + (wn + ni*16 + l16)*64 + s0);
      for (int mi=0;mi<4;++mi)
        for (int ni=0;ni<4;++ni)
          acc[mi][ni] = __builtin_amdgcn_mfma_f32_16x16x32_f16(af[mi], bfr[ni], acc[mi][ni], 0,0,0);
    }
    __syncthreads();
  }
  // ---- epilogue: stage tile to LDS (stride 130 f16) ----
  for (int mi=0;mi<4;++mi)
    for (int ni=0;ni<4;++ni)
      for (int r=0;r<4;++r)
        smem[(wm + mi*16 + quad*4 + r)*130 + wn + ni*16 + l16] = f2h(acc[mi][ni][r]);
  __syncthreads();
  const int sec = n0 >> 11;           // 0=Q, 1=K, 2=V
  const int hh  = (n0 & 2047) >> 7;
  const int bb  = m0 >> 11;
  const int s0g = m0 & 2047;
  const int bhg = bb*16 + hh;
  if (sec < 2){
    h16* dst = sec ? kT : qT;
    const int d = t & 63;
    const int g = t >> 6;
    const float inv = __expf(-0.14391157f * (float)d);   // ln(10000)/64
    for (int p=0;p<32;++p){
      int sr = p*4 + g;
      int s  = s0g + sr;
      float sn, cs; __sincosf((float)s * inv, &sn, &cs);
      float x1 = h2f(smem[sr*130 + d]);
      float x2 = h2f(smem[sr*130 + d + 64]);
      size_t o = ((size_t)bhg*2048 + s)*128 + d;
      dst[o]      = f2h(x1*cs - x2*sn);
      dst[o + 64] = f2h(x2*cs + x1*sn);
    }
  } else {
    const int sr = t & 127;             // lane = s -> stride 65 words: conflict-free
    const int g  = t >> 7;
    for (int p=0;p<64;++p){
      int d = p*2 + g;
      vT[((size_t)bhg*128 + d)*2048 + s0g + sr] = smem[sr*130 + d];
    }
  }
}

// ---------------- O-projection GEMM: f32 out (BK=64 swizzled) ------------
__global__ __launch_bounds__(256) void gemm_out(const h16* __restrict__ A,
                                                const h16* __restrict__ Bt,
                                                float* __restrict__ Cout){
  const int K = 2048, N = 2048;
  __shared__ h16 a_lds[128*64];
  __shared__ h16 b_lds[128*64];
  const int t = threadIdx.x;
  const int m0 = blockIdx.y * 128, n0 = blockIdx.x * 128;
  const int wave = t >> 6, lane = t & 63, quad = lane >> 4, l16 = lane & 15;
  const int wm = (wave & 1) * 64, wn = (wave >> 1) * 64;
  const int l3 = lane >> 3, c7 = lane & 7;
  const int xorc = c7 ^ l3;
  const h16* Ab = A  + (size_t)(m0 + wave*8 + l3)*K + xorc*8;
  const h16* Bb = Bt + (size_t)(n0 + wave*8 + l3)*K + xorc*8;
  h16* aL = a_lds + wave*512;
  h16* bL = b_lds + wave*512;

  floatx4 zero4 = {0.f,0.f,0.f,0.f};
  floatx4 acc[4][4];
  for (int mi=0;mi<4;++mi) for (int ni=0;ni<4;++ni) acc[mi][ni] = zero4;

  for (int k0 = 0; k0 < K; k0 += 64){
    for (int p=0;p<4;++p){
      GL2LDS(Ab + (size_t)p*32*K + k0, aL + p*2048);
      GL2LDS(Bb + (size_t)p*32*K + k0, bL + p*2048);
    }
    __syncthreads();
    for (int kk=0; kk<2; ++kk){
      const int s0 = ((kk*4 + quad) ^ (l16 & 7)) * 8;
      half8 af[4], bfr[4];
      for (int mi=0;mi<4;++mi) af[mi]  = *(const half8*)(a_lds + (wm + mi*16 + l16)*64 + s0);
      for (int ni=0;ni<4;++ni) bfr[ni] = *(const half8*)(b_lds + (wn + ni*16 + l16)*64 + s0);
      for (int mi=0;mi<4;++mi)
        for (int ni=0;ni<4;++ni)
          acc[mi][ni] = __builtin_amdgcn_mfma_f32_16x16x32_f16(af[mi], bfr[ni], acc[mi][ni], 0,0,0);
    }
    __syncthreads();
  }
  for (int mi=0;mi<4;++mi)
    for (int ni=0;ni<4;++ni)
      for (int r=0;r<4;++r){
        int row = m0 + wm + mi*16 + quad*4 + r;
        int col = n0 + wn + ni*16 + l16;
        Cout[(size_t)row*N + col] = acc[mi][ni][r];
      }
}

// ---------------- flash attention (lingvo softmax + tanh cap) ------------
// Online softmax with running max (REQUIRED: P stored f16 for PV MFMA —
// fixed-m underflows f16; R6 lesson). MFMA row-sum via ones-rows.
// grid (16, h, b); block pairs q-tiles {x, 31-x} -> 33 kt per block.
__global__ __launch_bounds__(256) void flash_attn(const h16* __restrict__ qT,
                                                  const h16* __restrict__ kT,
                                                  const h16* __restrict__ vT,
                                                  h16* __restrict__ O){
  __shared__ h16 k_lds[64*136];    // [kn][kd], pad 128 -> 136
  __shared__ h16 v_lds[144*72];    // [d][s], rows 128..143 = ones
  __shared__ h16 p_lds[4*16*72];   // per-wave 16 x 64 (pad 72)
  const int t = threadIdx.x, wave = t>>6, lane = t&63, quad = lane>>4, l16 = lane&15;
  const int h = blockIdx.y, b = blockIdx.z;
  const int bh = b*16 + h;
  const int krow = t>>4, kch = t&15;
  const int vrow = t>>3, vch = t&7;
  const h16* kTb = kT + (size_t)bh*2048*128;
  const h16* vTb = vT + (size_t)bh*128*2048;
  floatx4 zero4 = {0.f,0.f,0.f,0.f};
  // ones rows for the MFMA row-sum trick
  for (int i = t; i < 16*64; i += 256)
    v_lds[(128 + (i>>6))*72 + (i&63)] = (h16)1.0f;
  __syncthreads();

  for (int half = 0; half < 2; ++half){
    const int qt = half ? 31 - (int)blockIdx.x : (int)blockIdx.x;
    const int q0 = qt*64;
    const size_t qrow = (size_t)bh*2048 + q0 + wave*16 + l16;
    half8 aq[4];
    for (int kc=0;kc<4;++kc) aq[kc] = *(const half8*)(qT + qrow*128 + kc*32 + quad*8);
    floatx4 acc_o[8];
    for (int nt=0;nt<8;++nt) acc_o[nt] = zero4;
    floatx4 acc_l = zero4;              // row-sum accumulator
    float mrow[4] = {0.f,0.f,0.f,0.f};  // lingvo: max clamped at 0

    half8 kreg[4], vreg[4];
    for (int p=0;p<4;++p){
      kreg[p] = *(const half8*)(kTb + (size_t)(p*16 + krow)*128 + kch*8);
      vreg[p] = *(const half8*)(vTb + (size_t)(p*32 + vrow)*2048 + vch*8);
    }

    for (int kt = 0; kt <= qt; ++kt){
      const int kbase = kt*64;
      __syncthreads();
      for (int p=0;p<4;++p){
        *(half8*)(k_lds + (p*16 + krow)*136 + kch*8) = kreg[p];
        *(half8*)(v_lds + (p*32 + vrow)*72  + vch*8) = vreg[p];
      }
      __syncthreads();
      if (kt < qt){
        const int nb = kbase + 64;
        for (int p=0;p<4;++p){
          kreg[p] = *(const half8*)(kTb + (size_t)(nb + p*16 + krow)*128 + kch*8);
          vreg[p] = *(const half8*)(vTb + (size_t)(p*32 + vrow)*2048 + nb + vch*8);
        }
      }
      floatx4 s[4];
      for (int ni=0;ni<4;++ni){
        floatx4 a = zero4;
        for (int kc=0;kc<4;++kc){
          half8 bk = *(const half8*)(k_lds + (ni*16 + l16)*136 + kc*32 + quad*8);
          a = __builtin_amdgcn_mfma_f32_16x16x32_f16(aq[kc], bk, a, 0,0,0);
        }
        s[ni] = a;
      }
      float pm[4][4];
      float tmax[4] = {-1e30f,-1e30f,-1e30f,-1e30f};
      const bool diag = (kt == qt);
      for (int ni=0;ni<4;++ni){
        int col = kbase + ni*16 + l16;
        for (int r=0;r<4;++r){
          float e = __expf(s[ni][r] * 0.04f);          // 50*tanh(x/50)
          float x = 50.f - 100.f * __builtin_amdgcn_rcpf(e + 1.f);
          if (diag){
            int row = q0 + wave*16 + quad*4 + r;
            if (col > row) x = -1e30f;
          }
          pm[ni][r] = x;
          tmax[r] = fmaxf(tmax[r], x);
        }
      }
      for (int r=0;r<4;++r)
        for (int off=1; off<16; off<<=1)
          tmax[r] = fmaxf(tmax[r], __shfl_xor(tmax[r], off, 16));
      float alpha[4], mnew[4];
      for (int r=0;r<4;++r){
        mnew[r] = fmaxf(mrow[r], tmax[r]);
        alpha[r] = __expf(mrow[r] - mnew[r]);
        mrow[r] = mnew[r];
      }
      for (int ni=0;ni<4;++ni)
        for (int r=0;r<4;++r)
          pm[ni][r] = __expf(pm[ni][r] - mnew[r]);
      for (int nt=0;nt<8;++nt)
        for (int r=0;r<4;++r) acc_o[nt][r] *= alpha[r];
      for (int r=0;r<4;++r) acc_l[r] *= alpha[r];
      h16* pw = p_lds + wave*16*72;
      for (int ni=0;ni<4;++ni)
        for (int r=0;r<4;++r)
          pw[(quad*4+r)*72 + ni*16 + l16] = f2h(pm[ni][r]);
      __builtin_amdgcn_wave_barrier();
      half8 ap0 = *(const half8*)(pw + l16*72 + quad*8);
      half8 ap1 = *(const half8*)(pw + l16*72 + 32 + quad*8);
      for (int nt=0;nt<8;++nt){
        half8 bv0 = *(const half8*)(v_lds + (nt*16 + l16)*72 + quad*8);
        half8 bv1 = *(const half8*)(v_lds + (nt*16 + l16)*72 + 32 + quad*8);
        acc_o[nt] = __builtin_amdgcn_mfma_f32_16x16x32_f16(ap0, bv0, acc_o[nt], 0,0,0);
        acc_o[nt] = __builtin_amdgcn_mfma_f32_16x16x32_f16(ap1, bv1, acc_o[nt], 0,0,0);
      }
      { // row-sum via ones rows 128..143
        half8 bo0 = *(const half8*)(v_lds + (128 + l16)*72 + quad*8);
        half8 bo1 = *(const half8*)(v_lds + (128 + l16)*72 + 32 + quad*8);
        acc_l = __builtin_amdgcn_mfma_f32_16x16x32_f16(ap0, bo0, acc_l, 0,0,0);
        acc_l = __builtin_amdgcn_mfma_f32_16x16x32_f16(ap1, bo1, acc_l, 0,0,0);
      }
    }
    float invl[4];
    for (int r=0;r<4;++r) invl[r] = 1.0f / (acc_l[r] + __expf(-mrow[r]));
    for (int nt=0;nt<8;++nt)
      for (int r=0;r<4;++r){
        int row = q0 + wave*16 + quad*4 + r;
        int col = h*128 + nt*16 + l16;
        O[((size_t)b*2048 + row)*2048 + col] = f2h(acc_o[nt][r] * invl[r]);
      }
  }
}

extern "C" void kernel_launch(void* const* d_in, const int* in_sizes, int n_in,
                              void* d_out, int out_size, void* d_ws, size_t ws_size,
                              hipStream_t stream){
  (void)in_sizes; (void)n_in; (void)out_size; (void)ws_size;
  const float* hs = (const float*)d_in[0];
  const float* wq = (const float*)d_in[1];
  const float* wk = (const float*)d_in[2];
  const float* wv = (const float*)d_in[3];
  const float* wo = (const float*)d_in[4];

  char* ws = (char*)d_ws;
  size_t off = 0;
  h16* hs_f   = (h16*)(ws + off); off += (size_t)4096*2048*2;
  h16* wqkv_t = (h16*)(ws + off); off += (size_t)6144*2048*2;
  h16* wo_t   = (h16*)(ws + off); off += (size_t)2048*2048*2;
  h16* qT     = (h16*)(ws + off); off += (size_t)4096*2048*2;
  h16* kT     = (h16*)(ws + off); off += (size_t)4096*2048*2;
  h16* vT     = (h16*)(ws + off); off += (size_t)4096*2048*2;
  h16* obuf   = (h16*)(ws + off); off += (size_t)4096*2048*2;

  prep<<<dim3(32,32,5), 256, 0, stream>>>(wq, wk, wv, wo, hs, wqkv_t, wo_t, hs_f);
  gemm_qkv<<<dim3(48,32), 256, 0, stream>>>(hs_f, wqkv_t, qT, kT, vT);
  flash_attn<<<dim3(16,16,2), 256, 0, stream>>>(qT, kT, vT, obuf);
  gemm_out<<<dim3(16,32), 256, 0, stream>>>(obuf, wo_t, (float*)d_out);
}